// Round 5
// baseline (266.550 us; speedup 1.0000x reference)
//
#include <hip/hip_runtime.h>
#include <hip/hip_bf16.h>
#include <math.h>

#define NT 1200
#define NB 16384
#define NY 8
#define NGROUPS (NT * NB)                 // 19,660,800 channel-groups
#define NQ      (NT * NB * NY / 4)        // 39,321,600 float4 elements
#define GRID    2048
#define BLOCK   256
#define STRIDE  (GRID * BLOCK)            // 524288; NQ = 75 * STRIDE exactly
#define UNROLL  5
#define NITER   15                        // 75 / UNROLL
#define W_LOW  0.2f
#define W_HIGH 1.75f

typedef float f32x4 __attribute__((ext_vector_type(4)));

// Stage 1: coalesced grid-stride (one float4/lane/load), unrolled x5 so each
// thread keeps 10 global_load_dwordx4 in flight (MLP) before consuming.
// Thread parity (tid&1) decides whether its float4 is channels 0-3 or 4-7
// (STRIDE is even, so parity is invariant across iterations).
__global__ __launch_bounds__(BLOCK) void rmse_partial_kernel(
    const float* __restrict__ outp, const float* __restrict__ tgtp,
    float* __restrict__ ws)
{
    const f32x4* __restrict__ o4 = reinterpret_cast<const f32x4*>(outp);
    const f32x4* __restrict__ t4 = reinterpret_cast<const f32x4*>(tgtp);

    const int q0 = blockIdx.x * BLOCK + threadIdx.x;

    f32x4 acc = {0.0f, 0.0f, 0.0f, 0.0f};

#pragma unroll 1
    for (int it = 0; it < NITER; ++it) {
        const int qb = q0 + it * (STRIDE * UNROLL);

        f32x4 a[UNROLL], b[UNROLL];
#pragma unroll
        for (int u = 0; u < UNROLL; ++u) {
            a[u] = o4[qb + u * STRIDE];
            b[u] = t4[qb + u * STRIDE];
        }

#pragma unroll
        for (int u = 0; u < UNROLL; ++u) {
            const int q   = qb + u * STRIDE;
            const int t   = q >> 15;                // q / (NB*NY/4)
            const int mon = t % 12;
            const float w2 = (mon >= 6 && mon <= 9) ? (W_HIGH * W_HIGH)
                                                    : (W_LOW * W_LOW);
            f32x4 d = a[u] - b[u];
            acc += (w2 * d) * d;
        }
    }

    // XOR-butterfly with even masks: reduces within each parity class.
#pragma unroll
    for (int mask = 2; mask <= 32; mask <<= 1) {
        acc.x += __shfl_xor(acc.x, mask, 64);
        acc.y += __shfl_xor(acc.y, mask, 64);
        acc.z += __shfl_xor(acc.z, mask, 64);
        acc.w += __shfl_xor(acc.w, mask, 64);
    }
    // Lane 0 holds ch0-3 sum of its wave, lane 1 holds ch4-7 sum.

    __shared__ float sh[4][NY];                     // 4 waves per block
    const int wave = threadIdx.x >> 6;
    const int lane = threadIdx.x & 63;
    if (lane < 2) {
        sh[wave][lane * 4 + 0] = acc.x;
        sh[wave][lane * 4 + 1] = acc.y;
        sh[wave][lane * 4 + 2] = acc.z;
        sh[wave][lane * 4 + 3] = acc.w;
    }
    __syncthreads();

    if (threadIdx.x < NY) {
        const int c = threadIdx.x;
        float s = sh[0][c] + sh[1][c] + sh[2][c] + sh[3][c];
        atomicAdd(&ws[c], s);                       // device-scope by default
    }
}

// Stage 2: finalize — sum over channels of sqrt(mean).
__global__ void rmse_final_kernel(const float* __restrict__ ws, float* __restrict__ out)
{
    if (threadIdx.x == 0 && blockIdx.x == 0) {
        const float inv_n = 1.0f / (float)NGROUPS;  // mean over NT*NB per channel
        float s = 0.0f;
#pragma unroll
        for (int c = 0; c < NY; ++c)
            s += sqrtf(ws[c] * inv_n);
        out[0] = s;
    }
}

extern "C" void kernel_launch(void* const* d_in, const int* in_sizes, int n_in,
                              void* d_out, int out_size, void* d_ws, size_t ws_size,
                              hipStream_t stream) {
    const float* outp = (const float*)d_in[0];
    const float* tgtp = (const float*)d_in[1];
    float* ws  = (float*)d_ws;
    float* out = (float*)d_out;

    // Harness poisons d_ws once and never re-poisons between replays:
    // zero our 8 accumulators every call.
    (void)hipMemsetAsync(ws, 0, NY * sizeof(float), stream);

    rmse_partial_kernel<<<GRID, BLOCK, 0, stream>>>(outp, tgtp, ws);
    rmse_final_kernel<<<1, 64, 0, stream>>>(ws, out);
}

// Round 6
// 213.567 us; speedup vs baseline: 1.2481x; 1.2481x over previous
//
#include <hip/hip_runtime.h>
#include <hip/hip_bf16.h>
#include <math.h>

#define NT 1200
#define NB 16384
#define NY 8
#define NGROUPS (NT * NB)                 // 19,660,800 channel-groups
#define NQ      (NT * NB * NY / 4)        // 39,321,600 float4 elements
#define GRID    1536                      // 6 blocks/CU on 256 CUs, exactly uniform
#define BLOCK   256
#define NTHREADS (GRID * BLOCK)           // 393,216
#define CHUNK   4                         // 4 consecutive float4 = 64 B per array per iter
#define NITER   (NQ / (NTHREADS * CHUNK)) // 25, exact — no tail
#define W_LOW  0.2f
#define W_HIGH 1.75f

typedef float f32x4 __attribute__((ext_vector_type(4)));

// Stage 1: each thread reads 64 B CONTIGUOUS per array per iteration
// (4 consecutive dwordx4 -> 8 loads in flight, spatially adjacent).
// Chunk c covers float4s [4c..4c+3] = 4 channel-groups: f4 even -> ch0-3,
// f4 odd -> ch4-7 (same mapping for every thread). 8192 chunks per timestep,
// so one seasonal weight per iteration: t = c >> 13.
__global__ __launch_bounds__(BLOCK) void rmse_partial_kernel(
    const float* __restrict__ outp, const float* __restrict__ tgtp,
    float* __restrict__ ws)
{
    const f32x4* __restrict__ o4 = reinterpret_cast<const f32x4*>(outp);
    const f32x4* __restrict__ t4 = reinterpret_cast<const f32x4*>(tgtp);

    const int c0 = blockIdx.x * BLOCK + threadIdx.x;

    f32x4 accA = {0.0f, 0.0f, 0.0f, 0.0f};   // channels 0-3
    f32x4 accB = {0.0f, 0.0f, 0.0f, 0.0f};   // channels 4-7

#pragma unroll 1
    for (int it = 0; it < NITER; ++it) {
        const int c   = c0 + it * NTHREADS;   // chunk index
        const int qb  = c << 2;               // first float4 of chunk
        const int t   = c >> 13;              // timestep (8192 chunks per t)
        const int mon = t % 12;
        const float w2 = (mon >= 6 && mon <= 9) ? (W_HIGH * W_HIGH)
                                                : (W_LOW * W_LOW);

        f32x4 a0 = o4[qb + 0];
        f32x4 a1 = o4[qb + 1];
        f32x4 a2 = o4[qb + 2];
        f32x4 a3 = o4[qb + 3];
        f32x4 b0 = t4[qb + 0];
        f32x4 b1 = t4[qb + 1];
        f32x4 b2 = t4[qb + 2];
        f32x4 b3 = t4[qb + 3];

        f32x4 d0 = a0 - b0;
        f32x4 d1 = a1 - b1;
        f32x4 d2 = a2 - b2;
        f32x4 d3 = a3 - b3;

        accA += (w2 * d0) * d0;
        accB += (w2 * d1) * d1;
        accA += (w2 * d2) * d2;
        accB += (w2 * d3) * d3;
    }

    // Full 64-lane XOR butterfly — every thread has the same channel mapping.
#pragma unroll
    for (int mask = 1; mask <= 32; mask <<= 1) {
        accA.x += __shfl_xor(accA.x, mask, 64);
        accA.y += __shfl_xor(accA.y, mask, 64);
        accA.z += __shfl_xor(accA.z, mask, 64);
        accA.w += __shfl_xor(accA.w, mask, 64);
        accB.x += __shfl_xor(accB.x, mask, 64);
        accB.y += __shfl_xor(accB.y, mask, 64);
        accB.z += __shfl_xor(accB.z, mask, 64);
        accB.w += __shfl_xor(accB.w, mask, 64);
    }

    __shared__ float sh[4][NY];               // 4 waves per 256-thread block
    const int wave = threadIdx.x >> 6;
    const int lane = threadIdx.x & 63;
    if (lane == 0) {
        sh[wave][0] = accA.x; sh[wave][1] = accA.y;
        sh[wave][2] = accA.z; sh[wave][3] = accA.w;
        sh[wave][4] = accB.x; sh[wave][5] = accB.y;
        sh[wave][6] = accB.z; sh[wave][7] = accB.w;
    }
    __syncthreads();

    if (threadIdx.x < NY) {
        const int ch = threadIdx.x;
        float s = sh[0][ch] + sh[1][ch] + sh[2][ch] + sh[3][ch];
        atomicAdd(&ws[ch], s);                // device-scope by default
    }
}

// Stage 2: finalize — sum over channels of sqrt(mean).
__global__ void rmse_final_kernel(const float* __restrict__ ws, float* __restrict__ out)
{
    if (threadIdx.x == 0 && blockIdx.x == 0) {
        const float inv_n = 1.0f / (float)NGROUPS;   // mean over NT*NB per channel
        float s = 0.0f;
#pragma unroll
        for (int c = 0; c < NY; ++c)
            s += sqrtf(ws[c] * inv_n);
        out[0] = s;
    }
}

extern "C" void kernel_launch(void* const* d_in, const int* in_sizes, int n_in,
                              void* d_out, int out_size, void* d_ws, size_t ws_size,
                              hipStream_t stream) {
    const float* outp = (const float*)d_in[0];
    const float* tgtp = (const float*)d_in[1];
    float* ws  = (float*)d_ws;
    float* out = (float*)d_out;

    // Harness poisons d_ws once and never re-poisons between replays:
    // zero our 8 accumulators every call.
    (void)hipMemsetAsync(ws, 0, NY * sizeof(float), stream);

    rmse_partial_kernel<<<GRID, BLOCK, 0, stream>>>(outp, tgtp, ws);
    rmse_final_kernel<<<1, 64, 0, stream>>>(ws, out);
}